// Round 10
// baseline (200.345 us; speedup 1.0000x reference)
//
#include <hip/hip_runtime.h>
#include <math.h>

#define NPTS 65536

__device__ __forceinline__ float4 ld4_guard(const float* __restrict__ row, int pos, int hi) {
    float4 v;
    if (pos >= 0 && pos + 4 <= hi) {
        v = *(const float4*)(row + pos);
    } else {
        v.x = (pos + 0 >= 0 && pos + 0 < hi) ? row[pos + 0] : 0.f;
        v.y = (pos + 1 >= 0 && pos + 1 < hi) ? row[pos + 1] : 0.f;
        v.z = (pos + 2 >= 0 && pos + 2 < hi) ? row[pos + 2] : 0.f;
        v.w = (pos + 3 >= 0 && pos + 3 < hi) ? row[pos + 3] : 0.f;
    }
    return v;
}

// =====================================================================
// transpose x (B,N,2) -> x_t (N, 64)  [x_t[n][b*2+c] = x[b][n][c]]
// =====================================================================
__global__ __launch_bounds__(256) void transpose_kernel(const float* __restrict__ x,
                                                        float* __restrict__ xt)
{
    __shared__ float tile[64][65];
    int n0 = blockIdx.x * 64;
    int tid = threadIdx.x;
    int lane = tid & 63, w = tid >> 6;
    const float2* x2 = (const float2*)x;
#pragma unroll
    for (int bq = 0; bq < 8; ++bq) {
        int b = bq * 4 + w;
        float2 v = x2[(size_t)b * NPTS + n0 + lane];
        tile[lane][b * 2 + 0] = v.x;
        tile[lane][b * 2 + 1] = v.y;
    }
    __syncthreads();
    int f4 = tid & 15;
#pragma unroll
    for (int rq = 0; rq < 4; ++rq) {
        int r = rq * 16 + (tid >> 4);
        float4 v = make_float4(tile[r][f4 * 4 + 0], tile[r][f4 * 4 + 1],
                               tile[r][f4 * 4 + 2], tile[r][f4 * 4 + 3]);
        *(float4*)&xt[(size_t)(n0 + r) * 64 + f4 * 4] = v;
    }
}

// =====================================================================
// Fused smooth + conv0. Block = (b64, tile of 512 outputs).
// Phase1: stage ord indices; Phase2: gather 8B xt pairs (L2-resident);
// Phase3: smooth+tanh into s_s (LDS only, never HBM); Phase4: conv0.
// =====================================================================
__global__ __launch_bounds__(256) void conv0_fused(
    const float* __restrict__ xt,          // (N,64)
    const int* __restrict__ orderings,     // (2,N)
    const float* __restrict__ sp_w, const float* __restrict__ sp_b,
    const float* __restrict__ w,           // (4,2,32)
    const float* __restrict__ bias,
    float* __restrict__ out)               // (64,4,16388), valid l<16385
{
    constexpr int LTILE = 512;
    constexpr int SPAN = 4 * LTILE + 28;   // 2076
    constexpr int NT = 33;

    __shared__ int idx_s[SPAN + 2];
    __shared__ __align__(16) float rows[SPAN + 2][2];
    __shared__ __align__(16) float s_s[2][SPAN + 4];
    __shared__ float w_s[4][2][32];

    int bid = blockIdx.x;
    int tile = bid % NT;
    int b = bid / NT;                      // 0..63  (sfc = b>>5, batch = b&31)
    int tid = threadIdx.x;
    const int* ord = orderings + (size_t)(b >> 5) * NPTS;

    for (int i = tid; i < 4 * 2 * 32; i += 256) ((float*)w_s)[i] = w[i];

    int base = tile * (LTILE * 4) - 16;
    for (int k = tid; k < SPAN + 2; k += 256) {
        int g = base - 1 + k;
        g = g < 0 ? 0 : (g > NPTS - 1 ? NPTS - 1 : g);
        idx_s[k] = ord[g];
    }
    __syncthreads();

    int bc = 2 * (b & 31);
    for (int k = tid; k < SPAN + 2; k += 256) {
        float2 v = *(const float2*)&xt[(size_t)idx_s[k] * 64 + bc];
        rows[k][0] = v.x;
        rows[k][1] = v.y;
    }
    __syncthreads();

    for (int p = tid; p < SPAN; p += 256) {
        int pos = base + p;
        float s0 = 0.f, s1 = 0.f;
        if (pos >= 0 && pos < NPTS) {
            float w0 = sp_w[pos * 3 + 0], w1 = sp_w[pos * 3 + 1], w2 = sp_w[pos * 3 + 2];
            float bb = sp_b[pos];
            s0 = tanhf(w0 * rows[p][0] + w1 * rows[p + 1][0] + w2 * rows[p + 2][0] + bb);
            s1 = tanhf(w0 * rows[p][1] + w1 * rows[p + 1][1] + w2 * rows[p + 2][1] + bb);
        }
        s_s[0][p] = s0;
        s_s[1][p] = s1;
    }
    __syncthreads();

    int lofs = tid * 2;
    float acc[4][2];
#pragma unroll
    for (int c = 0; c < 4; ++c) {
        float bv = bias[c];
        acc[c][0] = bv; acc[c][1] = bv;
    }

#pragma unroll 1
    for (int ci = 0; ci < 2; ++ci) {
        float4 v[9];
#pragma unroll
        for (int k = 0; k < 9; ++k)
            v[k] = *(const float4*)&s_s[ci][4 * lofs + 4 * k];
#pragma unroll
        for (int k4 = 0; k4 < 8; ++k4) {
#pragma unroll
            for (int c = 0; c < 4; ++c) {
                const float* wk = &w_s[c][ci][4 * k4];
                float wx = wk[0], wy = wk[1], wz = wk[2], ww = wk[3];
                acc[c][0] += v[k4].x * wx + v[k4].y * wy + v[k4].z * wz + v[k4].w * ww;
                acc[c][1] += v[k4 + 1].x * wx + v[k4 + 1].y * wy + v[k4 + 1].z * wz + v[k4 + 1].w * ww;
            }
        }
    }

    int l0 = tile * LTILE + lofs;
#pragma unroll
    for (int c = 0; c < 4; ++c) {
        size_t row = ((size_t)b * 4 + c) * 16388;
        if (l0 + 1 < 16385) {
            float2 st2 = make_float2(tanhf(acc[c][0]), tanhf(acc[c][1]));
            *(float2*)&out[row + l0] = st2;
        } else if (l0 < 16385) {
            out[row + l0] = tanhf(acc[c][0]);
        }
    }
}

// =====================================================================
// LDS-staged conv (conv1): float4 staging, LPT=2 sliding outputs.
// =====================================================================
template <int CIN, int COUT, int LPT, int ISTR, int OSTR, int LIN, int LOUT>
__global__ __launch_bounds__(256, 2) void conv_lds(
    const float* __restrict__ in, const float* __restrict__ w,
    const float* __restrict__ bias, float* __restrict__ out)
{
    constexpr int LTILE = 256 * LPT;
    constexpr int SPAN = 4 * LTILE + 28;
    constexpr int NF4 = SPAN / 4;
    constexpr int NT = (LOUT + LTILE - 1) / LTILE;
    constexpr int NV = 8 + LPT - 1;

    __shared__ __align__(16) float in_s[CIN][SPAN];
    __shared__ float w_s[COUT][CIN][32];

    int bid = blockIdx.x;
    int tile = bid % NT;
    int b = bid / NT;
    int tid = threadIdx.x;

    for (int i = tid; i < COUT * CIN * 32; i += 256)
        ((float*)w_s)[i] = w[i];

    int base = tile * LTILE * 4 - 16;
    const float* inb = in + (size_t)b * CIN * ISTR;
    if (base >= 0 && base + SPAN <= LIN) {
        for (int q = tid; q < CIN * NF4; q += 256) {
            int ci = q / NF4, p = q - ci * NF4;
            *(float4*)&in_s[ci][4 * p] =
                *(const float4*)(inb + (size_t)ci * ISTR + base + 4 * p);
        }
    } else {
        for (int q = tid; q < CIN * SPAN; q += 256) {
            int ci = q / SPAN, p = q - ci * SPAN;
            int pos = base + p;
            in_s[ci][p] = (pos >= 0 && pos < LIN) ? inb[(size_t)ci * ISTR + pos] : 0.f;
        }
    }
    __syncthreads();

    int lofs = tid * LPT;
    float acc[COUT][LPT];
#pragma unroll
    for (int c = 0; c < COUT; ++c) {
        float bv = bias[c];
#pragma unroll
        for (int j = 0; j < LPT; ++j) acc[c][j] = bv;
    }

#pragma unroll 1
    for (int ci = 0; ci < CIN; ++ci) {
        float4 v[NV];
#pragma unroll
        for (int k = 0; k < NV; ++k)
            v[k] = *(const float4*)&in_s[ci][4 * lofs + 4 * k];
#pragma unroll
        for (int k4 = 0; k4 < 8; ++k4) {
#pragma unroll
            for (int c = 0; c < COUT; ++c) {
                const float* wk = &w_s[c][ci][4 * k4];
                float wx = wk[0], wy = wk[1], wz = wk[2], ww = wk[3];
#pragma unroll
                for (int j = 0; j < LPT; ++j)
                    acc[c][j] += v[k4 + j].x * wx + v[k4 + j].y * wy
                               + v[k4 + j].z * wz + v[k4 + j].w * ww;
            }
        }
    }

    int l0 = tile * LTILE + lofs;
#pragma unroll
    for (int c = 0; c < COUT; ++c) {
        size_t row = ((size_t)b * COUT + c) * OSTR;
        if (l0 + 1 < LOUT) {
            float2 st2 = make_float2(tanhf(acc[c][0]), tanhf(acc[c][1]));
            *(float2*)&out[row + l0] = st2;
        } else if (l0 < LOUT) {
            out[row + l0] = tanhf(acc[c][0]);
        }
    }
}

// =====================================================================
// Fused conv2+conv3 v3: 512 threads, block=(b, t in [0,8)) covering 33 l3.
// conv2 split (i,quarter)=640 units (all waves busy); w2 staged swizzled
// [ci][k4][co] (per-lane 16B-apart -> conflict-free); c2s stride 172;
// w3 staged into dead st region after conv2 -> conv3 pure LDS.
// =====================================================================
__global__ __launch_bounds__(512) void conv23_kernel(
    const float* __restrict__ c1,      // (B, 8, 4100), valid 4097
    const float* __restrict__ w2, const float* __restrict__ b2,
    const float* __restrict__ w3, const float* __restrict__ b3,
    float* __restrict__ c3out)         // (B, 16, 260), valid l3 < 257
{
    __shared__ __align__(16) float ubuf[8192];       // union: st[8][672] | w3s[8192]
    __shared__ __align__(16) float c2s[16][172];
    __shared__ __align__(16) float4 w2s[1024];       // [(ci*8+k4)*16 + co]

    float (*st)[672] = (float(*)[672])ubuf;
    const float4* w3s4 = (const float4*)ubuf;

    int b = blockIdx.x >> 3;
    int t = blockIdx.x & 7;
    int tid = threadIdx.x;

    int l3_0 = t * 33;
    int s2 = 4 * l3_0 - 16;
    int s1 = 4 * s2 - 16;

    // stage w2 swizzled: src (co,ci,k) -> dst ((ci*8+k4)*16+co)*4 + e
    for (int q = tid; q < 4096; q += 512) {
        int co = q >> 8, rem = q & 255, ci = rem >> 5, k = rem & 31;
        ((float*)w2s)[(((ci << 3) + (k >> 2)) * 16 + co) * 4 + (k & 3)] = w2[q];
    }
    // stage c1 window
    const float* c1b = c1 + (size_t)b * 8 * 4100;
    for (int q = tid; q < 8 * 167; q += 512) {
        int ci = q / 167, p = q - ci * 167;
        *(float4*)&st[ci][4 * p] = ld4_guard(c1b + (size_t)ci * 4100, s1 + 4 * p, 4097);
    }
    __syncthreads();

    // ---- conv2: 640 units = 160 positions x 4 quarters, 4 channels each ----
    for (int uq = tid; uq < 640; uq += 512) {
        int i = uq >> 2, qt = uq & 3, c0q = qt * 4;
        int l2 = s2 + i;
        bool valid = (l2 >= 0) && (l2 < 1025);
        float acc[4];
#pragma unroll
        for (int c = 0; c < 4; ++c) acc[c] = b2[c0q + c];
#pragma unroll 1
        for (int ci = 0; ci < 8; ++ci) {
            float4 v[8];
#pragma unroll
            for (int k = 0; k < 8; ++k)
                v[k] = *(const float4*)&st[ci][4 * i + 4 * k];
#pragma unroll
            for (int k4 = 0; k4 < 8; ++k4) {
#pragma unroll
                for (int c = 0; c < 4; ++c) {
                    float4 wv = w2s[((ci << 3) + k4) * 16 + c0q + c];
                    acc[c] += v[k4].x * wv.x + v[k4].y * wv.y
                            + v[k4].z * wv.z + v[k4].w * wv.w;
                }
            }
        }
#pragma unroll
        for (int c = 0; c < 4; ++c) c2s[c0q + c][i] = valid ? tanhf(acc[c]) : 0.f;
    }
    __syncthreads();

    // stage w3 into union (st is dead now)
    for (int q = tid; q < 8192; q += 512) ubuf[q] = w3[q];
    __syncthreads();

    // ---- conv3: 528 outputs (16 co x 33 l3), weights from LDS ----
    for (int q = tid; q < 528; q += 512) {
        int co = q / 33, j = q - co * 33;
        int l3 = l3_0 + j;
        if (l3 < 257) {
            float acc = b3[co];
#pragma unroll 1
            for (int ci = 0; ci < 16; ++ci) {
#pragma unroll
                for (int k4 = 0; k4 < 8; ++k4) {
                    float4 v = *(const float4*)&c2s[ci][4 * j + 4 * k4];
                    float4 wv = w3s4[(co * 16 + ci) * 8 + k4];
                    acc += v.x * wv.x + v.y * wv.y + v.z * wv.z + v.w * wv.w;
                }
            }
            c3out[((size_t)b * 16 + co) * 260 + l3] = tanhf(acc);
        }
    }
}

// =====================================================================
// conv4 + concat into feats. Block = (b, co-half). grid 128.
// =====================================================================
__global__ __launch_bounds__(256) void conv4_kernel(
    const float* __restrict__ c3,      // (B, 16, 260), valid l3 < 257
    const float* __restrict__ w4, const float* __restrict__ b4,
    float* __restrict__ feats)
{
    __shared__ __align__(16) float st[16][292];
    __shared__ float w4s[8][16][32];
    int b = blockIdx.x >> 1, h = blockIdx.x & 1;
    int tid = threadIdx.x;
    for (int i = tid; i < 8 * 16 * 32; i += 256) ((float*)w4s)[i] = w4[h * 4096 + i];
    const float* c3b = c3 + (size_t)b * 16 * 260;
    for (int q = tid; q < 16 * 72; q += 256) {
        int ci = q / 72, p = q - ci * 72;
        float4 v = ld4_guard(c3b + (size_t)ci * 260, 4 * p - 16, 257);
        *(float4*)&st[ci][4 * p] = v;
    }
    __syncthreads();
    for (int q = tid; q < 520; q += 256) {
        int co_l = q / 65, l4 = q - co_l * 65;
        int co = h * 8 + co_l;
        float acc = b4[co];
#pragma unroll 1
        for (int ci = 0; ci < 16; ++ci) {
#pragma unroll
            for (int k4 = 0; k4 < 8; ++k4) {
                float4 v = *(const float4*)&st[ci][4 * l4 + 4 * k4];
                const float* wk = &w4s[co_l][ci][4 * k4];
                acc += v.x * wk[0] + v.y * wk[1] + v.z * wk[2] + v.w * wk[3];
            }
        }
        feats[(size_t)(b & 31) * 2080 + (size_t)(b >> 5) * 1040 + co * 65 + l4]
            = tanhf(acc);
    }
}

// =====================================================================
// fc1: (32,2080) @ (128,2080)^T + b -> tanh. Wave per output, float4 dots.
// =====================================================================
__global__ __launch_bounds__(256) void fc1_kernel(const float* __restrict__ h,
                                                  const float* __restrict__ w,
                                                  const float* __restrict__ bias,
                                                  float* __restrict__ out)
{
    int lane = threadIdx.x & 63;
    int wid = blockIdx.x * 4 + (threadIdx.x >> 6);  // 0..1023
#pragma unroll
    for (int r = 0; r < 4; ++r) {
        int o = wid + r * 1024;
        int b = o >> 7, j = o & 127;
        const float4* h4 = (const float4*)(h + (size_t)b * 2080);
        const float4* w4 = (const float4*)(w + (size_t)j * 2080);
        float acc = 0.f;
#pragma unroll
        for (int q = 0; q < 8; ++q) {
            float4 a = h4[lane + 64 * q], c = w4[lane + 64 * q];
            acc += a.x * c.x + a.y * c.y + a.z * c.z + a.w * c.w;
        }
        if (lane < 8) {
            float4 a = h4[512 + lane], c = w4[512 + lane];
            acc += a.x * c.x + a.y * c.y + a.z * c.z + a.w * c.w;
        }
        for (int off = 32; off; off >>= 1) acc += __shfl_down(acc, off, 64);
        if (lane == 0) out[b * 128 + j] = tanhf(acc + bias[j]);
    }
}

// =====================================================================
// fc2: (32,128) @ (16,128)^T + b -> tanh. One wave per output.
// =====================================================================
__global__ __launch_bounds__(256) void fc2_kernel(const float* __restrict__ h,
                                                  const float* __restrict__ w,
                                                  const float* __restrict__ bias,
                                                  float* __restrict__ out)
{
    int lane = threadIdx.x & 63;
    int o = blockIdx.x * 4 + (threadIdx.x >> 6);  // 0..511
    int b = o >> 4, j = o & 15;
    const float* hb = h + (size_t)b * 128;
    const float* wj = w + (size_t)j * 128;
    float acc = hb[lane] * wj[lane] + hb[lane + 64] * wj[lane + 64];
    for (int off = 32; off; off >>= 1) acc += __shfl_down(acc, off, 64);
    if (lane == 0) out[o] = tanhf(acc + bias[j]);
}

extern "C" void kernel_launch(void* const* d_in, const int* in_sizes, int n_in,
                              void* d_out, int out_size, void* d_ws, size_t ws_size,
                              hipStream_t stream)
{
    const float* x = (const float*)d_in[0];
    const int* orderings = (const int*)d_in[1];
    const float* sp_w = (const float*)d_in[2];
    const float* sp_b = (const float*)d_in[3];
    const float* conv_w[5];
    const float* conv_b[5];
    for (int j = 0; j < 5; ++j) {
        conv_w[j] = (const float*)d_in[4 + 2 * j];
        conv_b[j] = (const float*)d_in[5 + 2 * j];
    }
    const float* fc1_w = (const float*)d_in[14];
    const float* fc1_b = (const float*)d_in[15];
    const float* fc2_w = (const float*)d_in[16];
    const float* fc2_b = (const float*)d_in[17];

    float* ws = (float*)d_ws;
    // workspace (floats), total 10,825,728 = 43.3 MB:
    size_t o_xt = 0;              // 4,194,304
    size_t o_c0 = 4194304;        // 64*4*16388 = 4,195,328
    size_t o_c1 = 8389632;        // 64*8*4100  = 2,099,200
    size_t o_c3 = 10488832;       // 64*16*260  =   266,240
    size_t o_f  = 10755072;       // 66,560
    size_t o_h1 = 10821632;       // 4,096

    transpose_kernel<<<NPTS / 64, 256, 0, stream>>>(x, ws + o_xt);

    conv0_fused<<<64 * 33, 256, 0, stream>>>(ws + o_xt, orderings, sp_w, sp_b,
                                             conv_w[0], conv_b[0], ws + o_c0);

    conv_lds<4, 8, 2, 16388, 4100, 16385, 4097>
        <<<64 * 9, 256, 0, stream>>>(ws + o_c0, conv_w[1], conv_b[1], ws + o_c1);

    conv23_kernel<<<64 * 8, 512, 0, stream>>>(ws + o_c1, conv_w[2], conv_b[2],
                                              conv_w[3], conv_b[3], ws + o_c3);

    conv4_kernel<<<128, 256, 0, stream>>>(ws + o_c3, conv_w[4], conv_b[4], ws + o_f);

    fc1_kernel<<<256, 256, 0, stream>>>(ws + o_f, fc1_w, fc1_b, ws + o_h1);
    fc2_kernel<<<128, 256, 0, stream>>>(ws + o_h1, fc2_w, fc2_b, (float*)d_out);
}

// Round 11
// 144.273 us; speedup vs baseline: 1.3887x; 1.3887x over previous
//
#include <hip/hip_runtime.h>
#include <math.h>

#define NPTS 65536

__device__ __forceinline__ float4 ld4_guard(const float* __restrict__ row, int pos, int hi) {
    float4 v;
    if (pos >= 0 && pos + 4 <= hi) {
        v = *(const float4*)(row + pos);
    } else {
        v.x = (pos + 0 >= 0 && pos + 0 < hi) ? row[pos + 0] : 0.f;
        v.y = (pos + 1 >= 0 && pos + 1 < hi) ? row[pos + 1] : 0.f;
        v.z = (pos + 2 >= 0 && pos + 2 < hi) ? row[pos + 2] : 0.f;
        v.w = (pos + 3 >= 0 && pos + 3 < hi) ? row[pos + 3] : 0.f;
    }
    return v;
}

// padded LDS mapping: insert 4 floats every 32 -> breaks 128B-stride bank aliasing,
// keeps 16B alignment (p%4==0 -> p'%4==0, float4 never crosses a pad).
__device__ __forceinline__ int pmap(int p) { return p + ((p >> 5) << 2); }

// =====================================================================
// transpose x (B,N,2) -> x_t (N, 64)
// =====================================================================
__global__ __launch_bounds__(256) void transpose_kernel(const float* __restrict__ x,
                                                        float* __restrict__ xt)
{
    __shared__ float tile[64][65];
    int n0 = blockIdx.x * 64;
    int tid = threadIdx.x;
    int lane = tid & 63, w = tid >> 6;
    const float2* x2 = (const float2*)x;
#pragma unroll
    for (int bq = 0; bq < 8; ++bq) {
        int b = bq * 4 + w;
        float2 v = x2[(size_t)b * NPTS + n0 + lane];
        tile[lane][b * 2 + 0] = v.x;
        tile[lane][b * 2 + 1] = v.y;
    }
    __syncthreads();
    int f4 = tid & 15;
#pragma unroll
    for (int rq = 0; rq < 4; ++rq) {
        int r = rq * 16 + (tid >> 4);
        float4 v = make_float4(tile[r][f4 * 4 + 0], tile[r][f4 * 4 + 1],
                               tile[r][f4 * 4 + 2], tile[r][f4 * 4 + 3]);
        *(float4*)&xt[(size_t)(n0 + r) * 64 + f4 * 4] = v;
    }
}

// =====================================================================
// smooth (one SFC): s[(b*2+c)*N + n] = tanh(...). Full-row 256B gather.
// =====================================================================
__global__ __launch_bounds__(256) void smooth_kernel(const float* __restrict__ xt,
                                                     const int* __restrict__ ord,
                                                     const float* __restrict__ sp_w,
                                                     const float* __restrict__ sp_b,
                                                     float* __restrict__ s)
{
    __shared__ int s_idx[130];
    __shared__ float rows[130][65];
    int n0 = blockIdx.x * 128;
    int tid = threadIdx.x;
    if (tid < 130) {
        int g = n0 - 1 + tid;
        g = g < 0 ? 0 : (g > NPTS - 1 ? NPTS - 1 : g);
        s_idx[tid] = ord[g];
    }
    __syncthreads();
    for (int q = tid; q < 130 * 16; q += 256) {
        int r = q >> 4, f4 = q & 15;
        float4 v = *(const float4*)&xt[(size_t)s_idx[r] * 64 + f4 * 4];
        rows[r][f4 * 4 + 0] = v.x; rows[r][f4 * 4 + 1] = v.y;
        rows[r][f4 * 4 + 2] = v.z; rows[r][f4 * 4 + 3] = v.w;
    }
    __syncthreads();
    int n_local = tid & 127, half = tid >> 7;
    int n = n0 + n_local;
    float w0 = sp_w[n * 3 + 0], w1 = sp_w[n * 3 + 1], w2 = sp_w[n * 3 + 2];
    float bb = sp_b[n];
#pragma unroll 4
    for (int bc = 0; bc < 64; bc += 2) {
        int bce = bc + half;
        float v = w0 * rows[n_local][bce] + w1 * rows[n_local + 1][bce]
                + w2 * rows[n_local + 2][bce] + bb;
        s[(size_t)bce * NPTS + n] = tanhf(v);
    }
}

// =====================================================================
// conv0 wave-per-co: 4 waves = 4 output channels; lane owns 8 consecutive l.
// Weights via readfirstlane -> SGPR (zero LDS ops in loop); input window in
// 15 float4 regs from padded LDS tile. NT=33 tiles of 512 outputs.
// =====================================================================
__global__ __launch_bounds__(256, 2) void conv0_wpc(
    const float* __restrict__ in,      // s: rows (b*2+ci)*NPTS
    const float* __restrict__ w,       // (4,2,32)
    const float* __restrict__ bias,
    float* __restrict__ out)           // (B,4,16388), valid l<16385
{
    constexpr int SPAN = 2076;                 // 4*512+28
    __shared__ float in_s[2][2336];            // pmap(2075)=2331 -> 2336

    int bid = blockIdx.x;
    int tile = bid % 33;
    int b = bid / 33;
    int tid = threadIdx.x;

    int base = tile * 2048 - 16;
    const float* inb = in + (size_t)b * 2 * NPTS;
    for (int q = tid; q < 2 * (SPAN / 4); q += 256) {
        int ci = q / (SPAN / 4), fp = q - ci * (SPAN / 4);
        int p = 4 * fp;
        float4 v = ld4_guard(inb + (size_t)ci * NPTS, base + p, NPTS);
        *(float4*)&in_s[ci][pmap(p)] = v;
    }
    __syncthreads();

    int lane = tid & 63;
    int co_u = __builtin_amdgcn_readfirstlane(tid >> 6);

    float acc[8];
    float bv = bias[co_u];
#pragma unroll
    for (int j = 0; j < 8; ++j) acc[j] = bv;

#pragma unroll 1
    for (int ci = 0; ci < 2; ++ci) {
        const float* wb = w + (co_u * 2 + ci) * 32;
        float wv[32];
#pragma unroll
        for (int k = 0; k < 32; ++k) wv[k] = wb[k];
        float4 v[15];
#pragma unroll
        for (int k = 0; k < 15; ++k)
            v[k] = *(const float4*)&in_s[ci][pmap(32 * lane + 4 * k)];
#pragma unroll
        for (int k4 = 0; k4 < 8; ++k4) {
            float wx = wv[4 * k4], wy = wv[4 * k4 + 1], wz = wv[4 * k4 + 2], ww = wv[4 * k4 + 3];
#pragma unroll
            for (int j = 0; j < 8; ++j)
                acc[j] += v[j + k4].x * wx + v[j + k4].y * wy
                        + v[j + k4].z * wz + v[j + k4].w * ww;
        }
    }

    int l0 = tile * 512 + lane * 8;
    size_t row = ((size_t)b * 4 + co_u) * 16388;
    if (l0 + 8 <= 16385) {
        float4 s0 = make_float4(tanhf(acc[0]), tanhf(acc[1]), tanhf(acc[2]), tanhf(acc[3]));
        float4 s1 = make_float4(tanhf(acc[4]), tanhf(acc[5]), tanhf(acc[6]), tanhf(acc[7]));
        *(float4*)&out[row + l0] = s0;
        *(float4*)&out[row + l0 + 4] = s1;
    } else {
#pragma unroll
        for (int j = 0; j < 8; ++j)
            if (l0 + j < 16385) out[row + l0 + j] = tanhf(acc[j]);
    }
}

// =====================================================================
// conv1 wave-per-co: 512 threads = 8 waves = 8 co; lane owns 4 consecutive l.
// NT=17 tiles of 256 outputs.
// =====================================================================
__global__ __launch_bounds__(512) void conv1_wpc(
    const float* __restrict__ in,      // c0 (B,4,16388), valid 16385
    const float* __restrict__ w,       // (8,4,32)
    const float* __restrict__ bias,
    float* __restrict__ out)           // (B,8,4100), valid l<4097
{
    constexpr int SPAN = 1052;                 // 4*256+28
    __shared__ float in_s[4][1184];            // pmap(1051)=1179 -> 1184

    int bid = blockIdx.x;
    int tile = bid % 17;
    int b = bid / 17;
    int tid = threadIdx.x;

    int base = tile * 1024 - 16;
    const float* inb = in + (size_t)b * 4 * 16388;
    for (int q = tid; q < 4 * (SPAN / 4); q += 512) {
        int ci = q / (SPAN / 4), fp = q - ci * (SPAN / 4);
        int p = 4 * fp;
        float4 v = ld4_guard(inb + (size_t)ci * 16388, base + p, 16385);
        *(float4*)&in_s[ci][pmap(p)] = v;
    }
    __syncthreads();

    int lane = tid & 63;
    int co_u = __builtin_amdgcn_readfirstlane(tid >> 6);

    float acc[4];
    float bv = bias[co_u];
#pragma unroll
    for (int j = 0; j < 4; ++j) acc[j] = bv;

#pragma unroll 1
    for (int ci = 0; ci < 4; ++ci) {
        const float* wb = w + (co_u * 4 + ci) * 32;
        float wv[32];
#pragma unroll
        for (int k = 0; k < 32; ++k) wv[k] = wb[k];
        float4 v[11];
#pragma unroll
        for (int k = 0; k < 11; ++k)
            v[k] = *(const float4*)&in_s[ci][pmap(16 * lane + 4 * k)];
#pragma unroll
        for (int k4 = 0; k4 < 8; ++k4) {
            float wx = wv[4 * k4], wy = wv[4 * k4 + 1], wz = wv[4 * k4 + 2], ww = wv[4 * k4 + 3];
#pragma unroll
            for (int j = 0; j < 4; ++j)
                acc[j] += v[j + k4].x * wx + v[j + k4].y * wy
                        + v[j + k4].z * wz + v[j + k4].w * ww;
        }
    }

    int l0 = tile * 256 + lane * 4;
    size_t row = ((size_t)b * 8 + co_u) * 4100;
    if (l0 + 4 <= 4097) {
        float4 s0 = make_float4(tanhf(acc[0]), tanhf(acc[1]), tanhf(acc[2]), tanhf(acc[3]));
        *(float4*)&out[row + l0] = s0;
    } else {
#pragma unroll
        for (int j = 0; j < 4; ++j)
            if (l0 + j < 4097) out[row + l0 + j] = tanhf(acc[j]);
    }
}

// =====================================================================
// Fused conv2+conv3 (round-10 v3): 512 threads, block=(b, t in [0,8)).
// =====================================================================
__global__ __launch_bounds__(512) void conv23_kernel(
    const float* __restrict__ c1,      // (B, 8, 4100), valid 4097
    const float* __restrict__ w2, const float* __restrict__ b2,
    const float* __restrict__ w3, const float* __restrict__ b3,
    float* __restrict__ c3out)         // (B, 16, 260), valid l3 < 257
{
    __shared__ __align__(16) float ubuf[8192];       // st[8][672] | w3s
    __shared__ __align__(16) float c2s[16][172];
    __shared__ __align__(16) float4 w2s[1024];

    float (*st)[672] = (float(*)[672])ubuf;
    const float4* w3s4 = (const float4*)ubuf;

    int b = blockIdx.x >> 3;
    int t = blockIdx.x & 7;
    int tid = threadIdx.x;

    int l3_0 = t * 33;
    int s2 = 4 * l3_0 - 16;
    int s1 = 4 * s2 - 16;

    for (int q = tid; q < 4096; q += 512) {
        int co = q >> 8, rem = q & 255, ci = rem >> 5, k = rem & 31;
        ((float*)w2s)[(((ci << 3) + (k >> 2)) * 16 + co) * 4 + (k & 3)] = w2[q];
    }
    const float* c1b = c1 + (size_t)b * 8 * 4100;
    for (int q = tid; q < 8 * 167; q += 512) {
        int ci = q / 167, p = q - ci * 167;
        *(float4*)&st[ci][4 * p] = ld4_guard(c1b + (size_t)ci * 4100, s1 + 4 * p, 4097);
    }
    __syncthreads();

    for (int uq = tid; uq < 640; uq += 512) {
        int i = uq >> 2, qt = uq & 3, c0q = qt * 4;
        int l2 = s2 + i;
        bool valid = (l2 >= 0) && (l2 < 1025);
        float acc[4];
#pragma unroll
        for (int c = 0; c < 4; ++c) acc[c] = b2[c0q + c];
#pragma unroll 1
        for (int ci = 0; ci < 8; ++ci) {
            float4 v[8];
#pragma unroll
            for (int k = 0; k < 8; ++k)
                v[k] = *(const float4*)&st[ci][4 * i + 4 * k];
#pragma unroll
            for (int k4 = 0; k4 < 8; ++k4) {
#pragma unroll
                for (int c = 0; c < 4; ++c) {
                    float4 wv = w2s[((ci << 3) + k4) * 16 + c0q + c];
                    acc[c] += v[k4].x * wv.x + v[k4].y * wv.y
                            + v[k4].z * wv.z + v[k4].w * wv.w;
                }
            }
        }
#pragma unroll
        for (int c = 0; c < 4; ++c) c2s[c0q + c][i] = valid ? tanhf(acc[c]) : 0.f;
    }
    __syncthreads();

    for (int q = tid; q < 8192; q += 512) ubuf[q] = w3[q];
    __syncthreads();

    for (int q = tid; q < 528; q += 512) {
        int co = q / 33, j = q - co * 33;
        int l3 = l3_0 + j;
        if (l3 < 257) {
            float acc = b3[co];
#pragma unroll 1
            for (int ci = 0; ci < 16; ++ci) {
#pragma unroll
                for (int k4 = 0; k4 < 8; ++k4) {
                    float4 v = *(const float4*)&c2s[ci][4 * j + 4 * k4];
                    float4 wv = w3s4[(co * 16 + ci) * 8 + k4];
                    acc += v.x * wv.x + v.y * wv.y + v.z * wv.z + v.w * wv.w;
                }
            }
            c3out[((size_t)b * 16 + co) * 260 + l3] = tanhf(acc);
        }
    }
}

// =====================================================================
// conv4 + concat into feats. Block = (b, co-half).
// =====================================================================
__global__ __launch_bounds__(256) void conv4_kernel(
    const float* __restrict__ c3,      // (B, 16, 260), valid l3 < 257
    const float* __restrict__ w4, const float* __restrict__ b4,
    float* __restrict__ feats, int ibase)
{
    __shared__ __align__(16) float st[16][292];
    __shared__ float w4s[8][16][32];
    int b = blockIdx.x >> 1, h = blockIdx.x & 1;
    int tid = threadIdx.x;
    for (int i = tid; i < 8 * 16 * 32; i += 256) ((float*)w4s)[i] = w4[h * 4096 + i];
    const float* c3b = c3 + (size_t)b * 16 * 260;
    for (int q = tid; q < 16 * 72; q += 256) {
        int ci = q / 72, p = q - ci * 72;
        float4 v = ld4_guard(c3b + (size_t)ci * 260, 4 * p - 16, 257);
        *(float4*)&st[ci][4 * p] = v;
    }
    __syncthreads();
    for (int q = tid; q < 520; q += 256) {
        int co_l = q / 65, l4 = q - co_l * 65;
        int co = h * 8 + co_l;
        float acc = b4[co];
#pragma unroll 1
        for (int ci = 0; ci < 16; ++ci) {
#pragma unroll
            for (int k4 = 0; k4 < 8; ++k4) {
                float4 v = *(const float4*)&st[ci][4 * l4 + 4 * k4];
                const float* wk = &w4s[co_l][ci][4 * k4];
                acc += v.x * wk[0] + v.y * wk[1] + v.z * wk[2] + v.w * wk[3];
            }
        }
        feats[(size_t)(b & 31) * 2080 + (size_t)((b >> 5) + ibase) * 1040 + co * 65 + l4]
            = tanhf(acc);
    }
}

// =====================================================================
// fc1 / fc2
// =====================================================================
__global__ __launch_bounds__(256) void fc1_kernel(const float* __restrict__ h,
                                                  const float* __restrict__ w,
                                                  const float* __restrict__ bias,
                                                  float* __restrict__ out)
{
    int lane = threadIdx.x & 63;
    int wid = blockIdx.x * 4 + (threadIdx.x >> 6);
#pragma unroll
    for (int r = 0; r < 4; ++r) {
        int o = wid + r * 1024;
        int b = o >> 7, j = o & 127;
        const float4* h4 = (const float4*)(h + (size_t)b * 2080);
        const float4* w4 = (const float4*)(w + (size_t)j * 2080);
        float acc = 0.f;
#pragma unroll
        for (int q = 0; q < 8; ++q) {
            float4 a = h4[lane + 64 * q], c = w4[lane + 64 * q];
            acc += a.x * c.x + a.y * c.y + a.z * c.z + a.w * c.w;
        }
        if (lane < 8) {
            float4 a = h4[512 + lane], c = w4[512 + lane];
            acc += a.x * c.x + a.y * c.y + a.z * c.z + a.w * c.w;
        }
        for (int off = 32; off; off >>= 1) acc += __shfl_down(acc, off, 64);
        if (lane == 0) out[b * 128 + j] = tanhf(acc + bias[j]);
    }
}

__global__ __launch_bounds__(256) void fc2_kernel(const float* __restrict__ h,
                                                  const float* __restrict__ w,
                                                  const float* __restrict__ bias,
                                                  float* __restrict__ out)
{
    int lane = threadIdx.x & 63;
    int o = blockIdx.x * 4 + (threadIdx.x >> 6);
    int b = o >> 4, j = o & 15;
    const float* hb = h + (size_t)b * 128;
    const float* wj = w + (size_t)j * 128;
    float acc = hb[lane] * wj[lane] + hb[lane + 64] * wj[lane + 64];
    for (int off = 32; off; off >>= 1) acc += __shfl_down(acc, off, 64);
    if (lane == 0) out[o] = tanhf(acc + bias[j]);
}

extern "C" void kernel_launch(void* const* d_in, const int* in_sizes, int n_in,
                              void* d_out, int out_size, void* d_ws, size_t ws_size,
                              hipStream_t stream)
{
    const float* x = (const float*)d_in[0];
    const int* orderings = (const int*)d_in[1];
    const float* sp_w = (const float*)d_in[2];
    const float* sp_b = (const float*)d_in[3];
    const float* conv_w[5];
    const float* conv_b[5];
    for (int j = 0; j < 5; ++j) {
        conv_w[j] = (const float*)d_in[4 + 2 * j];
        conv_b[j] = (const float*)d_in[5 + 2 * j];
    }
    const float* fc1_w = (const float*)d_in[14];
    const float* fc1_b = (const float*)d_in[15];
    const float* fc2_w = (const float*)d_in[16];
    const float* fc2_b = (const float*)d_in[17];

    float* ws = (float*)d_ws;

    if (ws_size >= 12583936ull * 4ull) {
        // ---------- big path: merged B=64, 50.34 MB ----------
        // c0 [0, 4,195,328) (xt [0,4.19M) dead before conv0 writes)
        // s  [4,195,328, 12,583,936) ; c1 over dead s ; c3/f/h1 after c1.
        size_t o_xt = 0, o_c0 = 0, o_s = 4195328;
        size_t o_c1 = 4195328, o_c3 = 6294528, o_f = 6560768, o_h1 = 6627328;

        transpose_kernel<<<NPTS / 64, 256, 0, stream>>>(x, ws + o_xt);
        smooth_kernel<<<512, 256, 0, stream>>>(ws + o_xt, orderings, sp_w, sp_b, ws + o_s);
        smooth_kernel<<<512, 256, 0, stream>>>(ws + o_xt, orderings + NPTS, sp_w, sp_b,
                                               ws + o_s + 4194304);

        conv0_wpc<<<64 * 33, 256, 0, stream>>>(ws + o_s, conv_w[0], conv_b[0], ws + o_c0);
        conv1_wpc<<<64 * 17, 512, 0, stream>>>(ws + o_c0, conv_w[1], conv_b[1], ws + o_c1);
        conv23_kernel<<<64 * 8, 512, 0, stream>>>(ws + o_c1, conv_w[2], conv_b[2],
                                                  conv_w[3], conv_b[3], ws + o_c3);
        conv4_kernel<<<128, 256, 0, stream>>>(ws + o_c3, conv_w[4], conv_b[4],
                                              ws + o_f, 0);
        fc1_kernel<<<256, 256, 0, stream>>>(ws + o_f, fc1_w, fc1_b, ws + o_h1);
        fc2_kernel<<<128, 256, 0, stream>>>(ws + o_h1, fc2_w, fc2_b, (float*)d_out);
    } else {
        // ---------- small path: per-SFC, 42.2 MB ----------
        // xt [0,4.19M) live ; s [4.19M, 8.39M) ; c0 [8.39M, 10,486,272)
        // c1 [4,194,304, 5,243,904) over dead s ; c3 [5,243,904, 5,377,024)
        // f [10,486,272, 10,552,832) ; h1 next.
        size_t o_xt = 0, o_s = 4194304, o_c0 = 8388608;
        size_t o_c1 = 4194304, o_c3 = 5243904, o_f = 10486272, o_h1 = 10552832;

        transpose_kernel<<<NPTS / 64, 256, 0, stream>>>(x, ws + o_xt);
        for (int i = 0; i < 2; ++i) {
            smooth_kernel<<<512, 256, 0, stream>>>(ws + o_xt, orderings + (size_t)i * NPTS,
                                                   sp_w, sp_b, ws + o_s);
            conv0_wpc<<<32 * 33, 256, 0, stream>>>(ws + o_s, conv_w[0], conv_b[0], ws + o_c0);
            conv1_wpc<<<32 * 17, 512, 0, stream>>>(ws + o_c0, conv_w[1], conv_b[1], ws + o_c1);
            conv23_kernel<<<32 * 8, 512, 0, stream>>>(ws + o_c1, conv_w[2], conv_b[2],
                                                      conv_w[3], conv_b[3], ws + o_c3);
            conv4_kernel<<<64, 256, 0, stream>>>(ws + o_c3, conv_w[4], conv_b[4],
                                                 ws + o_f, i);
        }
        fc1_kernel<<<256, 256, 0, stream>>>(ws + o_f, fc1_w, fc1_b, ws + o_h1);
        fc2_kernel<<<128, 256, 0, stream>>>(ws + o_h1, fc2_w, fc2_b, (float*)d_out);
    }
}